// Round 2
// baseline (745.217 us; speedup 1.0000x reference)
//
#include <hip/hip_runtime.h>
#include <math.h>

#define L    4096
#define DI   128
#define NS   16
#define KK   6
#define DTR  4
#define CM   64   // d_model

__device__ __forceinline__ float softplus_f(float x){
    return x > 20.f ? x : __logf(1.f + __expf(x));
}
__device__ __forceinline__ float silu_f(float x){
    return x / (1.f + __expf(-x));
}

// ---------------- diag permutation ----------------
// diag_idx[l] = row-major position p of the l-th element in stable
// anti-diagonal order (ties by increasing row).
__global__ void k_diag(int* __restrict__ diag_idx){
    int p = blockIdx.x*256 + threadIdx.x;
    if(p >= L) return;
    int h = p >> 6, w = p & 63, s = h + w;
    int imin = s > 63 ? s - 63 : 0;
    // count of elements on diagonals < s
    int off = (s < 64) ? (s*(s+1))/2 : 4096 - ((127-s)*(128-s))/2;
    diag_idx[off + (h - imin)] = p;
}

// ---------------- in_proj ----------------
__global__ __launch_bounds__(256) void k_inproj(const float* __restrict__ x,
                                                const float* __restrict__ W_in,
                                                float* __restrict__ xx,
                                                float* __restrict__ sz){
    int p = blockIdx.x;
    int o = threadIdx.x;
    __shared__ float xr[CM];
    if(o < CM) xr[o] = x[p*CM + o];
    __syncthreads();
    const float* wr = W_in + o*CM;
    float acc = 0.f;
    #pragma unroll
    for(int c=0;c<CM;c++) acc += xr[c]*wr[c];
    if(o < DI) xx[o*L + p] = acc;
    else       sz[p*DI + (o-DI)] = silu_f(acc);
}

// ---------------- depthwise conv 3x3 SAME + bias + SiLU ----------------
__global__ __launch_bounds__(256) void k_conv(const float* __restrict__ xx,
                                              const float* __restrict__ cw,
                                              const float* __restrict__ cb,
                                              float* __restrict__ xc){
    int idx = blockIdx.x*256 + threadIdx.x;   // d*L + p
    int d = idx >> 12, p = idx & (L-1);
    int h = p >> 6, w = p & 63;
    const float* wp = cw + d*9;
    const float* base = xx + d*L;
    float acc = cb[d];
    #pragma unroll
    for(int dh=-1; dh<=1; dh++){
        int hh = h+dh;
        if(hh < 0 || hh >= 64) continue;
        #pragma unroll
        for(int dw=-1; dw<=1; dw++){
            int ww = w+dw;
            if(ww < 0 || ww >= 64) continue;
            acc += wp[(dh+1)*3+(dw+1)] * base[hh*64+ww];
        }
    }
    xc[idx] = silu_f(acc);
}

// ---------------- materialize the 6 orderings ----------------
__global__ __launch_bounds__(256) void k_xs(const float* __restrict__ xc,
                                            const int* __restrict__ diag_idx,
                                            float* __restrict__ xs){
    int t = blockIdx.x*256 + threadIdx.x;     // ((k*DI+d)*L + l)
    int l = t & (L-1);
    int kd = t >> 12;
    int k = kd >> 7, d = kd & 127;
    int p;
    switch(k){
        case 0: p = l; break;
        case 1: p = ((l&63)<<6) | (l>>6); break;
        case 2: p = (L-1) - l; break;
        case 3: { int m = (L-1)-l; p = ((m&63)<<6) | (m>>6); } break;
        case 4: p = diag_idx[l]; break;
        default: p = diag_idx[l] ^ 63; break;   // W-flip within the row
    }
    xs[t] = xc[d*L + p];
}

// ---------------- projections: per (k,l) -> dts(4), Bs(16), Cs(16) ----------------
__global__ __launch_bounds__(256) void k_proj(const float* __restrict__ xs,
                                              const float* __restrict__ xpw,   // (K,36,DI)
                                              float* __restrict__ dts,         // (K,DTR,L)
                                              float* __restrict__ Bs,          // (K,NS,L)
                                              float* __restrict__ Cs){         // (K,NS,L)
    int k = blockIdx.x / (L/256);
    int l = (blockIdx.x % (L/256))*256 + threadIdx.x;
    const float* xsk = xs + k*DI*L;
    const float* wk  = xpw + k*36*DI;
    float acc[36];
    #pragma unroll
    for(int c=0;c<36;c++) acc[c] = 0.f;
    for(int d=0; d<DI; d++){
        float u = xsk[d*L + l];
        #pragma unroll
        for(int c=0;c<36;c++) acc[c] += wk[c*DI+d]*u;
    }
    #pragma unroll
    for(int r=0;r<DTR;r++) dts[(k*DTR+r)*L + l] = acc[r];
    #pragma unroll
    for(int n=0;n<NS;n++){
        Bs[(k*NS+n)*L + l] = acc[4+n];
        Cs[(k*NS+n)*L + l] = acc[20+n];
    }
}

// ---------------- chunked parallel selective scan ----------------
// block per (k,d); thread = (n = t&15, chunk c = t>>4); 16 chunks x 256 steps
#define DLS(l) ((l) + ((l)>>8))    // pad: stride between chunks 257 -> conflict-free
__global__ __launch_bounds__(256) void k_scan(const float* __restrict__ xs,
                                              const float* __restrict__ dts,   // (K,DTR,L)
                                              const float* __restrict__ Bs,
                                              const float* __restrict__ Cs,
                                              const float* __restrict__ dtw,   // (K,DI,DTR)
                                              const float* __restrict__ dtb,   // (K,DI)
                                              const float* __restrict__ A_logs,// (K*DI, NS)
                                              const float* __restrict__ Dsv,   // (K*DI)
                                              const int* __restrict__ diag_idx,
                                              float* __restrict__ y_sum){      // (L, DI)
    int k = blockIdx.x >> 7, d = blockIdx.x & 127;
    int t = threadIdx.x;
    int n = t & 15, c = t >> 4;
    const int CH = L/16;   // 256 steps per chunk

    __shared__ float dls[L + L/256];          // padded delta row
    __shared__ float aps[NS][16], xls[NS][16], inis[NS][16];

    // compute softplus(dtb + dtw*dts) once per block into LDS
    {
        float w0 = dtw[(k*DI+d)*DTR+0], w1 = dtw[(k*DI+d)*DTR+1];
        float w2 = dtw[(k*DI+d)*DTR+2], w3 = dtw[(k*DI+d)*DTR+3];
        float bb = dtb[k*DI+d];
        const float* r0 = dts + (k*DTR+0)*L;
        const float* r1 = dts + (k*DTR+1)*L;
        const float* r2 = dts + (k*DTR+2)*L;
        const float* r3 = dts + (k*DTR+3)*L;
        for(int j=t; j<L; j+=256){
            float dv = bb + w0*r0[j] + w1*r1[j] + w2*r2[j] + w3*r3[j];
            dls[DLS(j)] = softplus_f(dv);
        }
    }
    __syncthreads();

    float Av = -__expf(A_logs[(k*DI+d)*NS + n]);
    float Dv = Dsv[k*DI+d];
    const float* us = xs + (k*DI+d)*L;
    const float* Bp = Bs + (k*NS+n)*L;
    const float* Cp = Cs + (k*NS+n)*L;

    int l0 = c*CH;
    // phase 1: local scan from zero + running a-product
    float xv = 0.f, ap = 1.f;
    #pragma unroll 4
    for(int i=0;i<CH;i++){
        int l = l0+i;
        float dlt = dls[DLS(l)];
        float da  = __expf(dlt*Av);
        xv = da*xv + dlt*Bp[l]*us[l];
        ap *= da;
    }
    aps[n][c] = ap; xls[n][c] = xv;
    __syncthreads();
    // phase 2: per-n sequential combine over 16 chunks
    if(t < NS){
        float run = 0.f;
        #pragma unroll
        for(int cc=0; cc<16; cc++){
            inis[t][cc] = run;
            run = aps[t][cc]*run + xls[t][cc];
        }
    }
    __syncthreads();
    // phase 3: rescan with correct init, reduce over n, scatter-add
    xv = inis[n][c];
    #pragma unroll 4
    for(int i=0;i<CH;i++){
        int l = l0+i;
        float dlt = dls[DLS(l)];
        float u   = us[l];
        float da  = __expf(dlt*Av);
        xv = da*xv + dlt*Bp[l]*u;
        float y = xv * Cp[l];
        y += __shfl_xor(y, 1, 64);
        y += __shfl_xor(y, 2, 64);
        y += __shfl_xor(y, 4, 64);
        y += __shfl_xor(y, 8, 64);
        if(n == 0){
            int p;
            switch(k){
                case 0: p = l; break;
                case 1: p = ((l&63)<<6) | (l>>6); break;
                case 2: p = (L-1) - l; break;
                case 3: { int m = (L-1)-l; p = ((m&63)<<6) | (m>>6); } break;
                case 4: p = diag_idx[l]; break;
                default: p = (L-1) - diag_idx[l]; break;  // output perm for k=5
            }
            atomicAdd(&y_sum[p*DI + d], y + u*Dv);
        }
    }
}

// ---------------- LayerNorm + gate + out-proj ----------------
__global__ __launch_bounds__(128) void k_out(const float* __restrict__ y_sum,
                                             const float* __restrict__ sz,
                                             const float* __restrict__ ln_g,
                                             const float* __restrict__ ln_b,
                                             const float* __restrict__ W_out, // (CM,DI)
                                             float* __restrict__ out){        // (L,CM)
    int p = blockIdx.x, d = threadIdx.x;
    float y = y_sum[p*DI + d];
    float s1 = y, s2 = y*y;
    #pragma unroll
    for(int m=1;m<64;m<<=1){ s1 += __shfl_xor(s1,m,64); s2 += __shfl_xor(s2,m,64); }
    __shared__ float red[4];
    if((d&63)==0){ red[(d>>6)*2] = s1; red[(d>>6)*2+1] = s2; }
    __syncthreads();
    float mu  = (red[0]+red[2]) * (1.f/DI);
    float var = (red[1]+red[3]) * (1.f/DI) - mu*mu;
    float yh = (y-mu)*rsqrtf(var+1e-5f)*ln_g[d] + ln_b[d];
    __shared__ float ms[DI];
    ms[d] = yh * sz[p*DI+d];
    __syncthreads();
    if(d < CM){
        const float* wr = W_out + d*DI;
        float acc = 0.f;
        #pragma unroll
        for(int c=0;c<DI;c++) acc += ms[c]*wr[c];
        out[p*CM + d] = acc;
    }
}

extern "C" void kernel_launch(void* const* d_in, const int* in_sizes, int n_in,
                              void* d_out, int out_size, void* d_ws, size_t ws_size,
                              hipStream_t stream) {
    const float* x      = (const float*)d_in[0];
    const float* W_in   = (const float*)d_in[1];
    const float* conv_w = (const float*)d_in[2];
    const float* conv_b = (const float*)d_in[3];
    const float* xpw    = (const float*)d_in[4];
    const float* dtw    = (const float*)d_in[5];
    const float* dtb    = (const float*)d_in[6];
    const float* A_logs = (const float*)d_in[7];
    const float* Dsv    = (const float*)d_in[8];
    const float* ln_g   = (const float*)d_in[9];
    const float* ln_b   = (const float*)d_in[10];
    const float* W_out  = (const float*)d_in[11];
    float* out = (float*)d_out;

    float* ws = (float*)d_ws;
    float* xx   = ws;                       // DI*L   (dead after k_conv; aliased by ysum)
    float* sz   = xx   + DI*L;              // L*DI
    float* xc   = sz   + DI*L;              // DI*L
    float* xsb  = xc   + DI*L;              // KK*DI*L
    float* dts  = xsb  + KK*DI*L;           // KK*DTR*L
    float* Bsb  = dts  + KK*DTR*L;          // KK*NS*L
    float* Csb  = Bsb  + KK*NS*L;           // KK*NS*L
    int*   diag = (int*)(Csb + KK*NS*L);    // L ints
    float* ysum = xx;                       // alias

    k_diag  <<<L/256, 256, 0, stream>>>(diag);
    k_inproj<<<L, 256, 0, stream>>>(x, W_in, xx, sz);
    k_conv  <<<DI*L/256, 256, 0, stream>>>(xx, conv_w, conv_b, xc);
    hipMemsetAsync(ysum, 0, (size_t)L*DI*sizeof(float), stream);   // xx dead now
    k_xs    <<<KK*DI*L/256, 256, 0, stream>>>(xc, diag, xsb);
    k_proj  <<<KK*(L/256), 256, 0, stream>>>(xsb, xpw, dts, Bsb, Csb);
    k_scan  <<<KK*DI, 256, 0, stream>>>(xsb, dts, Bsb, Csb, dtw, dtb, A_logs, Dsv, diag, ysum);
    k_out   <<<L, 128, 0, stream>>>(ysum, sz, ln_g, ln_b, W_out, out);
}

// Round 3
// 220.905 us; speedup vs baseline: 3.3735x; 3.3735x over previous
//
#include <hip/hip_runtime.h>
#include <math.h>

#define L    4096
#define DI   128
#define NS   16
#define KK   6
#define DTR  4
#define CM   64    // d_model
#define NC   128   // scan chunks
#define CH   (L/NC) // 32 steps per chunk

__device__ __forceinline__ float softplus_f(float x){
    return x > 20.f ? x : __logf(1.f + __expf(x));
}
__device__ __forceinline__ float silu_f(float x){
    return x / (1.f + __expf(-x));
}

__device__ __forceinline__ int perm_in(int k, int l, const int* __restrict__ diag){
    switch(k){
        case 0: return l;
        case 1: return ((l&63)<<6) | (l>>6);
        case 2: return (L-1) - l;
        case 3: { int m = (L-1)-l; return ((m&63)<<6) | (m>>6); }
        case 4: return diag[l];
        default: return diag[l] ^ 63;
    }
}
__device__ __forceinline__ int perm_out(int k, int l, const int* __restrict__ diag){
    switch(k){
        case 0: return l;
        case 1: return ((l&63)<<6) | (l>>6);
        case 2: return (L-1) - l;
        case 3: { int m = (L-1)-l; return ((m&63)<<6) | (m>>6); }
        case 4: return diag[l];
        default: return (L-1) - diag[l];
    }
}

// ---------------- diag permutation ----------------
__global__ void k_diag(int* __restrict__ diag_idx){
    int p = blockIdx.x*256 + threadIdx.x;
    if(p >= L) return;
    int h = p >> 6, w = p & 63, s = h + w;
    int imin = s > 63 ? s - 63 : 0;
    int off = (s < 64) ? (s*(s+1))/2 : 4096 - ((127-s)*(128-s))/2;
    diag_idx[off + (h - imin)] = p;
}

// ---------------- in_proj: writes xx_t (p,d) and sz (p,d) ----------------
__global__ __launch_bounds__(256) void k_inproj(const float* __restrict__ x,
                                                const float* __restrict__ W_in,
                                                float* __restrict__ xx_t,
                                                float* __restrict__ sz){
    int p = blockIdx.x;
    int o = threadIdx.x;
    __shared__ float xr[CM];
    if(o < CM) xr[o] = x[p*CM + o];
    __syncthreads();
    const float* wr = W_in + o*CM;
    float acc = 0.f;
    #pragma unroll
    for(int c=0;c<CM;c++) acc += xr[c]*wr[c];
    if(o < DI) xx_t[p*DI + o] = acc;
    else       sz[p*DI + (o-DI)] = silu_f(acc);
}

// ---------------- depthwise conv 3x3 SAME + bias + SiLU, (p,d) layout ----------------
__global__ __launch_bounds__(256) void k_conv(const float* __restrict__ xx_t,
                                              const float* __restrict__ cw,
                                              const float* __restrict__ cb,
                                              float* __restrict__ xc_t){
    int idx = blockIdx.x*256 + threadIdx.x;   // p*DI + d
    int d = idx & 127, p = idx >> 7;
    int h = p >> 6, w = p & 63;
    float acc = cb[d];
    #pragma unroll
    for(int dh=-1; dh<=1; dh++){
        int hh = h+dh; if(hh < 0 || hh >= 64) continue;
        #pragma unroll
        for(int dw=-1; dw<=1; dw++){
            int ww = w+dw; if(ww < 0 || ww >= 64) continue;
            acc += cw[d*9 + (dh+1)*3+(dw+1)] * xx_t[(hh*64+ww)*DI + d];
        }
    }
    xc_t[idx] = silu_f(acc);
}

// ---------------- projections: gather rows of xc_t, produce dts/BT/CT ----------------
// block = (k, tile of 64 l); 256 threads; thread = (cgroup = t>>6 -> 9 c's, l = t&63)
#define XT_S 132
__global__ __launch_bounds__(256) void k_proj(const float* __restrict__ xc_t,
                                              const float* __restrict__ xpw,   // (K,36,DI)
                                              const int* __restrict__ diag,
                                              float* __restrict__ dts,         // (K,4,L)
                                              float* __restrict__ BT,          // (K,L,NS)
                                              float* __restrict__ CT){         // (K,L,NS)
    int k  = blockIdx.x >> 6;
    int l0 = (blockIdx.x & 63) * 64;
    int t  = threadIdx.x;
    __shared__ float xt[64*XT_S];
    // stage 64 permuted rows (coalesced float4)
    #pragma unroll
    for(int q=0;q<8;q++){
        int lin = q*256 + t;
        int row = lin >> 5, col4 = lin & 31;
        int p = perm_in(k, l0+row, diag);
        float4 v = ((const float4*)(xc_t + (size_t)p*DI))[col4];
        *((float4*)(xt + row*XT_S + col4*4)) = v;
    }
    __syncthreads();
    int l = t & 63, c0 = (t>>6)*9;
    const float* xr = xt + l*XT_S;
    float acc[9];
    #pragma unroll
    for(int j=0;j<9;j++) acc[j] = 0.f;
    const float4* wbase = (const float4*)(xpw + (size_t)k*36*DI);
    for(int dd4=0; dd4<32; dd4++){
        float4 xv = *((const float4*)(xr + dd4*4));
        #pragma unroll
        for(int j=0;j<9;j++){
            float4 wv = wbase[(c0+j)*32 + dd4];
            acc[j] += wv.x*xv.x + wv.y*xv.y + wv.z*xv.z + wv.w*xv.w;
        }
    }
    #pragma unroll
    for(int j=0;j<9;j++){
        int c = c0 + j;
        if(c < 4)        dts[((size_t)k*4 + c)*L + l0 + l] = acc[j];
        else if(c < 20)  BT[((size_t)k*L + l0 + l)*NS + (c-4)]  = acc[j];
        else             CT[((size_t)k*L + l0 + l)*NS + (c-20)] = acc[j];
    }
}

// ---------------- scan phase 1: per-chunk local scan ----------------
// block = k*NC + cc; 128 threads = one per d; 16 n-states per thread
__global__ __launch_bounds__(128) void k_scan1(const float* __restrict__ xc_t,
                                               const float* __restrict__ dts,
                                               const float* __restrict__ BT,
                                               const float* __restrict__ dtw,   // (K,DI,4)
                                               const float* __restrict__ dtb,   // (K,DI)
                                               const float* __restrict__ A_logs,// (K*DI,NS)
                                               const int* __restrict__ diag,
                                               float* __restrict__ apb,         // (K,NC,DI,NS)
                                               float* __restrict__ xlb){
    int bk = blockIdx.x;
    int k = bk >> 7, cc = bk & (NC-1);
    int d = threadIdx.x;
    int l0 = cc*CH;

    __shared__ float Bt[CH*NS];
    __shared__ float dtt[4*CH];
    __shared__ int   pt[CH];

    ((float4*)Bt)[d] = ((const float4*)(BT + ((size_t)k*L + l0)*NS))[d];
    { int r = d >> 5, i = d & (CH-1);
      dtt[r*CH + i] = dts[((size_t)k*4 + r)*L + l0 + i]; }
    if(d < CH) pt[d] = perm_in(k, l0+d, diag);
    __syncthreads();

    float4 w4 = ((const float4*)dtw)[(size_t)k*DI + d];
    float  bb = dtb[k*DI + d];
    float A[NS];
    {
        const float4* ar = (const float4*)(A_logs + ((size_t)k*DI + d)*NS);
        #pragma unroll
        for(int q=0;q<4;q++){
            float4 a4 = ar[q];
            A[q*4+0] = -__expf(a4.x); A[q*4+1] = -__expf(a4.y);
            A[q*4+2] = -__expf(a4.z); A[q*4+3] = -__expf(a4.w);
        }
    }
    float x[NS], ap[NS];
    #pragma unroll
    for(int n=0;n<NS;n++){ x[n] = 0.f; ap[n] = 1.f; }

    float u_nxt = xc_t[(size_t)pt[0]*DI + d];
    for(int i=0;i<CH;i++){
        float u = u_nxt;
        if(i+1 < CH) u_nxt = xc_t[(size_t)pt[i+1]*DI + d];
        float dv = bb + w4.x*dtt[i] + w4.y*dtt[CH+i] + w4.z*dtt[2*CH+i] + w4.w*dtt[3*CH+i];
        float delta = softplus_f(dv);
        float du = delta*u;
        const float* Bi = Bt + i*NS;
        #pragma unroll
        for(int n=0;n<NS;n++){
            float da = __expf(delta*A[n]);
            x[n] = da*x[n] + du*Bi[n];
            ap[n] *= da;
        }
    }
    float* apd = apb + ((size_t)bk*DI + d)*NS;
    float* xld = xlb + ((size_t)bk*DI + d)*NS;
    #pragma unroll
    for(int q=0;q<4;q++){
        ((float4*)apd)[q] = make_float4(ap[q*4],ap[q*4+1],ap[q*4+2],ap[q*4+3]);
        ((float4*)xld)[q] = make_float4(x[q*4], x[q*4+1], x[q*4+2], x[q*4+3]);
    }
}

// ---------------- scan phase 2: combine chunks; write ini in place of ap ----------------
__global__ __launch_bounds__(256) void k_comb(float* __restrict__ apb,
                                              const float* __restrict__ xlb){
    int tid = blockIdx.x*256 + threadIdx.x;   // K*DI*NS = 12288 threads
    int k = tid >> 11, rem = tid & 2047;      // rem = d*16+n
    size_t base = (size_t)k*NC*2048 + rem;    // +cc*2048 steps
    float run = 0.f;
    float a[8], xl[8];
    #pragma unroll
    for(int q=0;q<8;q++){ a[q] = apb[base + q*2048]; xl[q] = xlb[base + q*2048]; }
    for(int b=0; b<NC/8; b++){
        float a2[8], x2[8];
        if(b+1 < NC/8){
            #pragma unroll
            for(int q=0;q<8;q++){
                size_t off = base + (size_t)((b+1)*8+q)*2048;
                a2[q] = apb[off]; x2[q] = xlb[off];
            }
        }
        #pragma unroll
        for(int q=0;q<8;q++){
            size_t off = base + (size_t)(b*8+q)*2048;
            apb[off] = run;                 // ini
            run = a[q]*run + xl[q];
        }
        #pragma unroll
        for(int q=0;q<8;q++){ a[q] = a2[q]; xl[q] = x2[q]; }
    }
}

// ---------------- scan phase 3: rescan with init, emit y ----------------
__global__ __launch_bounds__(128) void k_scan2(const float* __restrict__ xc_t,
                                               const float* __restrict__ dts,
                                               const float* __restrict__ BT,
                                               const float* __restrict__ CT,
                                               const float* __restrict__ dtw,
                                               const float* __restrict__ dtb,
                                               const float* __restrict__ A_logs,
                                               const float* __restrict__ Dsv,   // (K*DI)
                                               const int* __restrict__ diag,
                                               const float* __restrict__ inib,  // = apb
                                               float* __restrict__ ysum){       // (L,DI)
    int bk = blockIdx.x;
    int k = bk >> 7, cc = bk & (NC-1);
    int d = threadIdx.x;
    int l0 = cc*CH;

    __shared__ float Bt[CH*NS];
    __shared__ float Ct[CH*NS];
    __shared__ float dtt[4*CH];
    __shared__ int   pt[CH];
    __shared__ int   po[CH];

    ((float4*)Bt)[d] = ((const float4*)(BT + ((size_t)k*L + l0)*NS))[d];
    ((float4*)Ct)[d] = ((const float4*)(CT + ((size_t)k*L + l0)*NS))[d];
    { int r = d >> 5, i = d & (CH-1);
      dtt[r*CH + i] = dts[((size_t)k*4 + r)*L + l0 + i]; }
    if(d < CH){ pt[d] = perm_in(k, l0+d, diag); po[d] = perm_out(k, l0+d, diag); }
    __syncthreads();

    float4 w4 = ((const float4*)dtw)[(size_t)k*DI + d];
    float  bb = dtb[k*DI + d];
    float  Dv = Dsv[k*DI + d];
    float A[NS];
    {
        const float4* ar = (const float4*)(A_logs + ((size_t)k*DI + d)*NS);
        #pragma unroll
        for(int q=0;q<4;q++){
            float4 a4 = ar[q];
            A[q*4+0] = -__expf(a4.x); A[q*4+1] = -__expf(a4.y);
            A[q*4+2] = -__expf(a4.z); A[q*4+3] = -__expf(a4.w);
        }
    }
    float x[NS];
    {
        const float4* ir = (const float4*)(inib + ((size_t)bk*DI + d)*NS);
        #pragma unroll
        for(int q=0;q<4;q++){
            float4 v = ir[q];
            x[q*4+0]=v.x; x[q*4+1]=v.y; x[q*4+2]=v.z; x[q*4+3]=v.w;
        }
    }

    float u_nxt = xc_t[(size_t)pt[0]*DI + d];
    for(int i=0;i<CH;i++){
        float u = u_nxt;
        if(i+1 < CH) u_nxt = xc_t[(size_t)pt[i+1]*DI + d];
        float dv = bb + w4.x*dtt[i] + w4.y*dtt[CH+i] + w4.z*dtt[2*CH+i] + w4.w*dtt[3*CH+i];
        float delta = softplus_f(dv);
        float du = delta*u;
        const float* Bi = Bt + i*NS;
        const float* Ci = Ct + i*NS;
        float y = 0.f;
        #pragma unroll
        for(int n=0;n<NS;n++){
            float da = __expf(delta*A[n]);
            x[n] = da*x[n] + du*Bi[n];
            y += x[n]*Ci[n];
        }
        atomicAdd(&ysum[(size_t)po[i]*DI + d], y + u*Dv);
    }
}

// ---------------- LayerNorm + gate + out-proj ----------------
__global__ __launch_bounds__(128) void k_out(const float* __restrict__ y_sum,
                                             const float* __restrict__ sz,
                                             const float* __restrict__ ln_g,
                                             const float* __restrict__ ln_b,
                                             const float* __restrict__ W_out, // (CM,DI)
                                             float* __restrict__ out){        // (L,CM)
    int p = blockIdx.x, d = threadIdx.x;
    float y = y_sum[p*DI + d];
    float s1 = y, s2 = y*y;
    #pragma unroll
    for(int m=1;m<64;m<<=1){ s1 += __shfl_xor(s1,m,64); s2 += __shfl_xor(s2,m,64); }
    __shared__ float red[4];
    if((d&63)==0){ red[(d>>6)*2] = s1; red[(d>>6)*2+1] = s2; }
    __syncthreads();
    float mu  = (red[0]+red[2]) * (1.f/DI);
    float var = (red[1]+red[3]) * (1.f/DI) - mu*mu;
    float yh = (y-mu)*rsqrtf(var+1e-5f)*ln_g[d] + ln_b[d];
    __shared__ float ms[DI];
    ms[d] = yh * sz[p*DI+d];
    __syncthreads();
    if(d < CM){
        const float* wr = W_out + d*DI;
        float acc = 0.f;
        #pragma unroll
        for(int c=0;c<DI;c++) acc += ms[c]*wr[c];
        out[p*CM + d] = acc;
    }
}

extern "C" void kernel_launch(void* const* d_in, const int* in_sizes, int n_in,
                              void* d_out, int out_size, void* d_ws, size_t ws_size,
                              hipStream_t stream) {
    const float* x      = (const float*)d_in[0];
    const float* W_in   = (const float*)d_in[1];
    const float* conv_w = (const float*)d_in[2];
    const float* conv_b = (const float*)d_in[3];
    const float* xpw    = (const float*)d_in[4];
    const float* dtw    = (const float*)d_in[5];
    const float* dtb    = (const float*)d_in[6];
    const float* A_logs = (const float*)d_in[7];
    const float* Dsv    = (const float*)d_in[8];
    const float* ln_g   = (const float*)d_in[9];
    const float* ln_b   = (const float*)d_in[10];
    const float* W_out  = (const float*)d_in[11];
    float* out = (float*)d_out;

    float* ws = (float*)d_ws;
    float* xx_t = ws;                        // L*DI (dead after k_conv; aliased by ysum)
    float* sz   = xx_t + (size_t)L*DI;       // L*DI
    float* xc_t = sz   + (size_t)L*DI;       // L*DI
    float* dts  = xc_t + (size_t)L*DI;       // K*4*L
    float* BT   = dts  + (size_t)KK*4*L;     // K*L*NS
    float* CT   = BT   + (size_t)KK*L*NS;    // K*L*NS
    float* apb  = CT   + (size_t)KK*L*NS;    // K*NC*DI*NS
    float* xlb  = apb  + (size_t)KK*NC*DI*NS;// K*NC*DI*NS
    int*   diag = (int*)(xlb + (size_t)KK*NC*DI*NS); // L ints
    float* ysum = xx_t;

    k_diag  <<<L/256, 256, 0, stream>>>(diag);
    k_inproj<<<L, 256, 0, stream>>>(x, W_in, xx_t, sz);
    k_conv  <<<(L*DI)/256, 256, 0, stream>>>(xx_t, conv_w, conv_b, xc_t);
    hipMemsetAsync(ysum, 0, (size_t)L*DI*sizeof(float), stream);   // xx_t dead now
    k_proj  <<<KK*64, 256, 0, stream>>>(xc_t, xpw, diag, dts, BT, CT);
    k_scan1 <<<KK*NC, 128, 0, stream>>>(xc_t, dts, BT, dtw, dtb, A_logs, diag, apb, xlb);
    k_comb  <<<KK*DI*NS/256, 256, 0, stream>>>(apb, xlb);
    k_scan2 <<<KK*NC, 128, 0, stream>>>(xc_t, dts, BT, CT, dtw, dtb, A_logs, Dsv, diag, apb, ysum);
    k_out   <<<L, 128, 0, stream>>>(ysum, sz, ln_g, ln_b, W_out, out);
}

// Round 4
// 195.056 us; speedup vs baseline: 3.8205x; 1.1325x over previous
//
#include <hip/hip_runtime.h>
#include <math.h>

#define L    4096
#define DI   128
#define NS   16
#define KK   6
#define DTR  4
#define CM   64    // d_model
#define NC   256   // scan chunks per direction
#define CH   (L/NC) // 16 steps per chunk

__device__ __forceinline__ float softplus_f(float x){
    return x > 20.f ? x : __logf(1.f + __expf(x));
}
__device__ __forceinline__ float silu_f(float x){
    return x / (1.f + __expf(-x));
}

// anti-diagonal rank of pixel p (inverse of diag_idx), closed form
__device__ __forceinline__ int rankp(int p){
    int h = p >> 6, w = p & 63, s = h + w;
    int imin = s > 63 ? s - 63 : 0;
    int off = (s < 64) ? (s*(s+1))/2 : 4096 - ((127-s)*(128-s))/2;
    return off + (h - imin);
}

__device__ __forceinline__ int perm_in(int k, int l, const int* __restrict__ diag){
    switch(k){
        case 0: return l;
        case 1: return ((l&63)<<6) | (l>>6);
        case 2: return (L-1) - l;
        case 3: { int m = (L-1)-l; return ((m&63)<<6) | (m>>6); }
        case 4: return diag[l];
        default: return diag[l] ^ 63;
    }
}

// ---------------- diag permutation table (scan order -> pixel) ----------------
__global__ void k_diag(int* __restrict__ diag_idx){
    int p = blockIdx.x*256 + threadIdx.x;
    if(p >= L) return;
    diag_idx[rankp(p)] = p;
}

// ---------------- in_proj: 16 pixels/block, W rows in registers ----------------
__global__ __launch_bounds__(256) void k_inproj(const float* __restrict__ x,
                                                const float* __restrict__ W_in,
                                                float* __restrict__ xx_t,
                                                float* __restrict__ sz){
    int pb = blockIdx.x * 16;
    int o  = threadIdx.x;
    __shared__ float xr[16][CM];
    ((float4*)&xr[0][0])[o] = ((const float4*)(x + (size_t)pb*CM))[o];
    float4 w[16];
    const float4* wrow = (const float4*)(W_in + (size_t)o*CM);
    #pragma unroll
    for(int q=0;q<16;q++) w[q] = wrow[q];
    __syncthreads();
    #pragma unroll
    for(int pi=0; pi<16; pi++){
        float acc = 0.f;
        const float4* xv4 = (const float4*)&xr[pi][0];
        #pragma unroll
        for(int q=0;q<16;q++){
            float4 xv = xv4[q];
            acc += w[q].x*xv.x + w[q].y*xv.y + w[q].z*xv.z + w[q].w*xv.w;
        }
        int p = pb + pi;
        if(o < DI) xx_t[(size_t)p*DI + o] = acc;
        else       sz[(size_t)p*DI + (o-DI)] = silu_f(acc);
    }
}

// ---------------- depthwise conv 3x3 SAME + bias + SiLU, (p,d) layout ----------------
__global__ __launch_bounds__(256) void k_conv(const float* __restrict__ xx_t,
                                              const float* __restrict__ cw,
                                              const float* __restrict__ cb,
                                              float* __restrict__ xc_t){
    int idx = blockIdx.x*256 + threadIdx.x;   // p*DI + d
    int d = idx & 127, p = idx >> 7;
    int h = p >> 6, w = p & 63;
    float acc = cb[d];
    #pragma unroll
    for(int dh=-1; dh<=1; dh++){
        int hh = h+dh; if(hh < 0 || hh >= 64) continue;
        #pragma unroll
        for(int dw=-1; dw<=1; dw++){
            int ww = w+dw; if(ww < 0 || ww >= 64) continue;
            acc += cw[d*9 + (dh+1)*3+(dw+1)] * xx_t[(size_t)(hh*64+ww)*DI + d];
        }
    }
    xc_t[idx] = silu_f(acc);
}

// ---------------- projections: gather rows of xc_t, produce dts/BT/CT ----------------
#define XT_S 132
__global__ __launch_bounds__(256) void k_proj(const float* __restrict__ xc_t,
                                              const float* __restrict__ xpw,   // (K,36,DI)
                                              const int* __restrict__ diag,
                                              float* __restrict__ dts,         // (K,4,L)
                                              float* __restrict__ BT,          // (K,L,NS)
                                              float* __restrict__ CT){         // (K,L,NS)
    int k  = blockIdx.x >> 6;
    int l0 = (blockIdx.x & 63) * 64;
    int t  = threadIdx.x;
    __shared__ float xt[64*XT_S];
    #pragma unroll
    for(int q=0;q<8;q++){
        int lin = q*256 + t;
        int row = lin >> 5, col4 = lin & 31;
        int p = perm_in(k, l0+row, diag);
        float4 v = ((const float4*)(xc_t + (size_t)p*DI))[col4];
        *((float4*)(xt + row*XT_S + col4*4)) = v;
    }
    __syncthreads();
    int l = t & 63, c0 = (t>>6)*9;
    const float* xr = xt + l*XT_S;
    float acc[9];
    #pragma unroll
    for(int j=0;j<9;j++) acc[j] = 0.f;
    const float4* wbase = (const float4*)(xpw + (size_t)k*36*DI);
    for(int dd4=0; dd4<32; dd4++){
        float4 xv = *((const float4*)(xr + dd4*4));
        #pragma unroll
        for(int j=0;j<9;j++){
            float4 wv = wbase[(c0+j)*32 + dd4];
            acc[j] += wv.x*xv.x + wv.y*xv.y + wv.z*xv.z + wv.w*xv.w;
        }
    }
    #pragma unroll
    for(int j=0;j<9;j++){
        int c = c0 + j;
        if(c < 4)        dts[((size_t)k*4 + c)*L + l0 + l] = acc[j];
        else if(c < 20)  BT[((size_t)k*L + l0 + l)*NS + (c-4)]  = acc[j];
        else             CT[((size_t)k*L + l0 + l)*NS + (c-20)] = acc[j];
    }
}

// ---------------- scan phase 1: per-chunk local scan ----------------
// block = k*NC + cc; 128 threads = one per d; 16 n-states per thread
__global__ __launch_bounds__(128) void k_scan1(const float* __restrict__ xc_t,
                                               const float* __restrict__ dts,
                                               const float* __restrict__ BT,
                                               const float* __restrict__ dtw,   // (K,DI,4)
                                               const float* __restrict__ dtb,   // (K,DI)
                                               const float* __restrict__ A_logs,// (K*DI,NS)
                                               const int* __restrict__ diag,
                                               float* __restrict__ apb,         // (K,NC,DI,NS)
                                               float* __restrict__ xlb){
    int bk = blockIdx.x;
    int k = bk >> 8, cc = bk & (NC-1);
    int d = threadIdx.x;
    int l0 = cc*CH;

    __shared__ float Bt[CH*NS];     // 256
    __shared__ float dtt[4*CH];     // 64
    __shared__ int   pt[CH];        // 16

    if(d < 64) ((float4*)Bt)[d] = ((const float4*)(BT + ((size_t)k*L + l0)*NS))[d];
    else { int j = d-64; int r = j>>4, i = j&15;
           dtt[j] = dts[((size_t)k*4 + r)*L + l0 + i]; }
    if(d < CH) pt[d] = perm_in(k, l0+d, diag);
    __syncthreads();

    float4 w4 = ((const float4*)dtw)[(size_t)k*DI + d];
    float  bb = dtb[k*DI + d];
    float A[NS];
    {
        const float4* ar = (const float4*)(A_logs + ((size_t)k*DI + d)*NS);
        #pragma unroll
        for(int q=0;q<4;q++){
            float4 a4 = ar[q];
            A[q*4+0] = -__expf(a4.x); A[q*4+1] = -__expf(a4.y);
            A[q*4+2] = -__expf(a4.z); A[q*4+3] = -__expf(a4.w);
        }
    }
    float x[NS], ap[NS];
    #pragma unroll
    for(int n=0;n<NS;n++){ x[n] = 0.f; ap[n] = 1.f; }

    float u_nxt = xc_t[(size_t)pt[0]*DI + d];
    #pragma unroll
    for(int i=0;i<CH;i++){
        float u = u_nxt;
        if(i+1 < CH) u_nxt = xc_t[(size_t)pt[i+1]*DI + d];
        float dv = bb + w4.x*dtt[i] + w4.y*dtt[CH+i] + w4.z*dtt[2*CH+i] + w4.w*dtt[3*CH+i];
        float delta = softplus_f(dv);
        float du = delta*u;
        const float* Bi = Bt + i*NS;
        #pragma unroll
        for(int n=0;n<NS;n++){
            float da = __expf(delta*A[n]);
            x[n] = da*x[n] + du*Bi[n];
            ap[n] *= da;
        }
    }
    float* apd = apb + ((size_t)bk*DI + d)*NS;
    float* xld = xlb + ((size_t)bk*DI + d)*NS;
    #pragma unroll
    for(int q=0;q<4;q++){
        ((float4*)apd)[q] = make_float4(ap[q*4],ap[q*4+1],ap[q*4+2],ap[q*4+3]);
        ((float4*)xld)[q] = make_float4(x[q*4], x[q*4+1], x[q*4+2], x[q*4+3]);
    }
}

// ---------------- scan phase 2: combine chunks; write ini in place of ap ----------------
__global__ __launch_bounds__(256) void k_comb(float* __restrict__ apb,
                                              const float* __restrict__ xlb){
    int tid = blockIdx.x*256 + threadIdx.x;   // K*DI*NS = 12288 threads
    int k = tid >> 11, rem = tid & 2047;      // rem = d*16+n
    size_t base = (size_t)k*NC*2048 + rem;
    float run = 0.f;
    float a[8], xl[8];
    #pragma unroll
    for(int q=0;q<8;q++){ a[q] = apb[base + (size_t)q*2048]; xl[q] = xlb[base + (size_t)q*2048]; }
    for(int b=0; b<NC/8; b++){
        float a2[8], x2[8];
        if(b+1 < NC/8){
            #pragma unroll
            for(int q=0;q<8;q++){
                size_t off = base + (size_t)((b+1)*8+q)*2048;
                a2[q] = apb[off]; x2[q] = xlb[off];
            }
        }
        #pragma unroll
        for(int q=0;q<8;q++){
            size_t off = base + (size_t)(b*8+q)*2048;
            apb[off] = run;                 // ini
            run = a[q]*run + xl[q];
        }
        #pragma unroll
        for(int q=0;q<8;q++){ a[q] = a2[q]; xl[q] = x2[q]; }
    }
}

// ---------------- scan phase 3: rescan with init, store y in scan order ----------------
__global__ __launch_bounds__(128) void k_scan2(const float* __restrict__ xc_t,
                                               const float* __restrict__ dts,
                                               const float* __restrict__ BT,
                                               const float* __restrict__ CT,
                                               const float* __restrict__ dtw,
                                               const float* __restrict__ dtb,
                                               const float* __restrict__ A_logs,
                                               const float* __restrict__ Dsv,   // (K*DI)
                                               const int* __restrict__ diag,
                                               const float* __restrict__ inib,  // = apb
                                               float* __restrict__ yk){         // (K,L,DI)
    int bk = blockIdx.x;
    int k = bk >> 8, cc = bk & (NC-1);
    int d = threadIdx.x;
    int l0 = cc*CH;

    __shared__ float Bt[CH*NS];
    __shared__ float Ct[CH*NS];
    __shared__ float dtt[4*CH];
    __shared__ int   pt[CH];

    if(d < 64){
        ((float4*)Bt)[d] = ((const float4*)(BT + ((size_t)k*L + l0)*NS))[d];
        int r = d>>4, i = d&15;
        dtt[d] = dts[((size_t)k*4 + r)*L + l0 + i];
    } else {
        ((float4*)Ct)[d-64] = ((const float4*)(CT + ((size_t)k*L + l0)*NS))[d-64];
    }
    if(d < CH) pt[d] = perm_in(k, l0+d, diag);
    __syncthreads();

    float4 w4 = ((const float4*)dtw)[(size_t)k*DI + d];
    float  bb = dtb[k*DI + d];
    float  Dv = Dsv[k*DI + d];
    float A[NS];
    {
        const float4* ar = (const float4*)(A_logs + ((size_t)k*DI + d)*NS);
        #pragma unroll
        for(int q=0;q<4;q++){
            float4 a4 = ar[q];
            A[q*4+0] = -__expf(a4.x); A[q*4+1] = -__expf(a4.y);
            A[q*4+2] = -__expf(a4.z); A[q*4+3] = -__expf(a4.w);
        }
    }
    float x[NS];
    {
        const float4* ir = (const float4*)(inib + ((size_t)bk*DI + d)*NS);
        #pragma unroll
        for(int q=0;q<4;q++){
            float4 v = ir[q];
            x[q*4+0]=v.x; x[q*4+1]=v.y; x[q*4+2]=v.z; x[q*4+3]=v.w;
        }
    }

    float u_nxt = xc_t[(size_t)pt[0]*DI + d];
    #pragma unroll
    for(int i=0;i<CH;i++){
        float u = u_nxt;
        if(i+1 < CH) u_nxt = xc_t[(size_t)pt[i+1]*DI + d];
        float dv = bb + w4.x*dtt[i] + w4.y*dtt[CH+i] + w4.z*dtt[2*CH+i] + w4.w*dtt[3*CH+i];
        float delta = softplus_f(dv);
        float du = delta*u;
        const float* Bi = Bt + i*NS;
        const float* Ci = Ct + i*NS;
        float y = 0.f;
        #pragma unroll
        for(int n=0;n<NS;n++){
            float da = __expf(delta*A[n]);
            x[n] = da*x[n] + du*Bi[n];
            y += x[n]*Ci[n];
        }
        yk[((size_t)k*L + l0 + i)*DI + d] = y + u*Dv;   // coalesced, no atomics
    }
}

// ---------------- gather 6 dirs + LayerNorm + gate + out-proj ----------------
__global__ __launch_bounds__(128) void k_out(const float* __restrict__ yk,
                                             const float* __restrict__ sz,
                                             const float* __restrict__ ln_g,
                                             const float* __restrict__ ln_b,
                                             const float* __restrict__ W_out, // (CM,DI)
                                             float* __restrict__ out){        // (L,CM)
    int pb = blockIdx.x*8;
    int d = threadIdx.x;
    __shared__ float ms[8][DI];
    __shared__ float red[8][2][2];
    float g = ln_g[d], bc = ln_b[d];
    float yv[8];
    #pragma unroll
    for(int pi=0;pi<8;pi++){
        int p = pb+pi;
        int tp = ((p&63)<<6) | (p>>6);
        float y;
        y  = yk[((size_t)0*L + p)*DI + d];
        y += yk[((size_t)1*L + tp)*DI + d];
        y += yk[((size_t)2*L + (L-1-p))*DI + d];
        y += yk[((size_t)3*L + (L-1-tp))*DI + d];
        y += yk[((size_t)4*L + rankp(p))*DI + d];
        y += yk[((size_t)5*L + rankp(L-1-p))*DI + d];
        yv[pi] = y;
        float s1 = y, s2 = y*y;
        #pragma unroll
        for(int m=1;m<64;m<<=1){ s1 += __shfl_xor(s1,m,64); s2 += __shfl_xor(s2,m,64); }
        if((d&63)==0){ red[pi][d>>6][0] = s1; red[pi][d>>6][1] = s2; }
    }
    __syncthreads();
    #pragma unroll
    for(int pi=0;pi<8;pi++){
        float mu  = (red[pi][0][0]+red[pi][1][0]) * (1.f/DI);
        float var = (red[pi][0][1]+red[pi][1][1]) * (1.f/DI) - mu*mu;
        float yh = (yv[pi]-mu)*rsqrtf(var+1e-5f)*g + bc;
        ms[pi][d] = yh * sz[(size_t)(pb+pi)*DI + d];
    }
    __syncthreads();
    int o = d & 63, hf = d >> 6;
    float4 w[32];
    const float4* wr4 = (const float4*)(W_out + (size_t)o*DI);
    #pragma unroll
    for(int q=0;q<32;q++) w[q] = wr4[q];
    for(int pi=hf; pi<8; pi+=2){
        float acc = 0.f;
        const float4* mr = (const float4*)ms[pi];
        #pragma unroll
        for(int q=0;q<32;q++){
            float4 xv = mr[q];
            acc += w[q].x*xv.x + w[q].y*xv.y + w[q].z*xv.z + w[q].w*xv.w;
        }
        out[(size_t)(pb+pi)*CM + o] = acc;
    }
}

extern "C" void kernel_launch(void* const* d_in, const int* in_sizes, int n_in,
                              void* d_out, int out_size, void* d_ws, size_t ws_size,
                              hipStream_t stream) {
    const float* x      = (const float*)d_in[0];
    const float* W_in   = (const float*)d_in[1];
    const float* conv_w = (const float*)d_in[2];
    const float* conv_b = (const float*)d_in[3];
    const float* xpw    = (const float*)d_in[4];
    const float* dtw    = (const float*)d_in[5];
    const float* dtb    = (const float*)d_in[6];
    const float* A_logs = (const float*)d_in[7];
    const float* Dsv    = (const float*)d_in[8];
    const float* ln_g   = (const float*)d_in[9];
    const float* ln_b   = (const float*)d_in[10];
    const float* W_out  = (const float*)d_in[11];
    float* out = (float*)d_out;

    float* ws = (float*)d_ws;
    float* xx_t = ws;                          // L*DI
    float* sz   = xx_t + (size_t)L*DI;         // L*DI
    float* xc_t = sz   + (size_t)L*DI;         // L*DI
    float* dts  = xc_t + (size_t)L*DI;         // K*4*L
    float* BT   = dts  + (size_t)KK*4*L;       // K*L*NS
    float* CT   = BT   + (size_t)KK*L*NS;      // K*L*NS
    float* apb  = CT   + (size_t)KK*L*NS;      // K*NC*DI*NS
    float* xlb  = apb  + (size_t)KK*NC*DI*NS;  // K*NC*DI*NS
    float* yk   = xlb  + (size_t)KK*NC*DI*NS;  // K*L*DI
    int*   diag = (int*)(yk + (size_t)KK*L*DI);// L ints

    k_diag  <<<L/256, 256, 0, stream>>>(diag);
    k_inproj<<<L/16, 256, 0, stream>>>(x, W_in, xx_t, sz);
    k_conv  <<<(L*DI)/256, 256, 0, stream>>>(xx_t, conv_w, conv_b, xc_t);
    k_proj  <<<KK*64, 256, 0, stream>>>(xc_t, xpw, diag, dts, BT, CT);
    k_scan1 <<<KK*NC, 128, 0, stream>>>(xc_t, dts, BT, dtw, dtb, A_logs, diag, apb, xlb);
    k_comb  <<<KK*DI*NS/256, 256, 0, stream>>>(apb, xlb);
    k_scan2 <<<KK*NC, 128, 0, stream>>>(xc_t, dts, BT, CT, dtw, dtb, A_logs, Dsv, diag, apb, yk);
    k_out   <<<L/8, 128, 0, stream>>>(yk, sz, ln_g, ln_b, W_out, out);
}